// Round 4
// baseline (690.665 us; speedup 1.0000x reference)
//
#include <hip/hip_runtime.h>
#include <hip/hip_bf16.h>

#define NH 24
#define HD 128
#define DM 3072
#define NB 2
#define SN 256
#define MR 512            // NB*SN rows
#define SCACHE 8192
#define NCH 9             // 8 cache chunks of 1024 + 1 new chunk of 256

typedef float f32x4 __attribute__((ext_vector_type(4)));
typedef float f32x2 __attribute__((ext_vector_type(2)));
typedef short s16x8 __attribute__((ext_vector_type(8)));
typedef short s16x4 __attribute__((ext_vector_type(4)));
typedef unsigned u32x4 __attribute__((ext_vector_type(4)));

__device__ __forceinline__ short bfc(float f) {
    __hip_bfloat16 h = __float2bfloat16(f);
    return __builtin_bit_cast(short, h);
}

// ---------------- GEMM: O[m,n] = sum_k A[m,k]*W[n,k] + bias[n] ----------------
// BM=64, BN=128, BK=64, 256 thr (4 waves), wave tile 32x64. Reg-staged prefetch.
__global__ __launch_bounds__(256, 3) void gemm_bias(
    const float* __restrict__ A,
    const float* __restrict__ W0, const float* __restrict__ W1, const float* __restrict__ W2,
    const float* __restrict__ b0, const float* __restrict__ b1, const float* __restrict__ b2,
    float* __restrict__ O0, float* __restrict__ O1, float* __restrict__ O2)
{
    const int z = blockIdx.z;
    const float* W    = (z == 0) ? W0 : (z == 1) ? W1 : W2;
    const float* bias = (z == 0) ? b0 : (z == 1) ? b1 : b2;
    float* O          = (z == 0) ? O0 : (z == 1) ? O1 : O2;

    const int n0 = blockIdx.x * 128;
    const int m0 = blockIdx.y * 64;
    const int t = threadIdx.x;
    const int lane = t & 63;
    const int wave = t >> 6;
    const int l15 = lane & 15, l4 = lane >> 4;
    const int wm = (wave >> 1) * 32, wn = (wave & 1) * 64;

    __shared__ short As[64][72];
    __shared__ short Bs[128][72];

    f32x4 acc[2][4] = {};
    f32x4 areg[4], breg[8];

    #pragma unroll
    for (int i = 0; i < 4; ++i) {
        int lin = i * 256 + t;
        areg[i] = *(const f32x4*)(A + (size_t)(m0 + (lin >> 4)) * DM + (lin & 15) * 4);
    }
    #pragma unroll
    for (int i = 0; i < 8; ++i) {
        int lin = i * 256 + t;
        breg[i] = *(const f32x4*)(W + (size_t)(n0 + (lin >> 4)) * DM + (lin & 15) * 4);
    }

    for (int ks = 0; ks < DM / 64; ++ks) {
        #pragma unroll
        for (int i = 0; i < 4; ++i) {
            int lin = i * 256 + t;
            s16x4 a4;
            #pragma unroll
            for (int j = 0; j < 4; ++j) a4[j] = bfc(areg[i][j]);
            *(s16x4*)&As[lin >> 4][(lin & 15) * 4] = a4;
        }
        #pragma unroll
        for (int i = 0; i < 8; ++i) {
            int lin = i * 256 + t;
            s16x4 w4;
            #pragma unroll
            for (int j = 0; j < 4; ++j) w4[j] = bfc(breg[i][j]);
            *(s16x4*)&Bs[lin >> 4][(lin & 15) * 4] = w4;
        }
        __syncthreads();
        if (ks + 1 < DM / 64) {
            int k0 = (ks + 1) * 64;
            #pragma unroll
            for (int i = 0; i < 4; ++i) {
                int lin = i * 256 + t;
                areg[i] = *(const f32x4*)(A + (size_t)(m0 + (lin >> 4)) * DM + k0 + (lin & 15) * 4);
            }
            #pragma unroll
            for (int i = 0; i < 8; ++i) {
                int lin = i * 256 + t;
                breg[i] = *(const f32x4*)(W + (size_t)(n0 + (lin >> 4)) * DM + k0 + (lin & 15) * 4);
            }
        }
        #pragma unroll
        for (int kt = 0; kt < 2; ++kt) {
            s16x8 af[2], bfr[4];
            #pragma unroll
            for (int i = 0; i < 2; ++i)
                af[i]  = *(const s16x8*)&As[wm + i * 16 + l15][kt * 32 + l4 * 8];
            #pragma unroll
            for (int i = 0; i < 4; ++i)
                bfr[i] = *(const s16x8*)&Bs[wn + i * 16 + l15][kt * 32 + l4 * 8];
            #pragma unroll
            for (int mi = 0; mi < 2; ++mi)
                #pragma unroll
                for (int ni = 0; ni < 4; ++ni)
                    acc[mi][ni] = __builtin_amdgcn_mfma_f32_16x16x32_bf16(
                        af[mi], bfr[ni], acc[mi][ni], 0, 0, 0);
        }
        __syncthreads();
    }

    #pragma unroll
    for (int ni = 0; ni < 4; ++ni) {
        int col = n0 + wn + ni * 16 + l15;
        float bv = bias[col];
        #pragma unroll
        for (int mi = 0; mi < 2; ++mi) {
            int row = m0 + wm + mi * 16 + l4 * 4;
            #pragma unroll
            for (int r = 0; r < 4; ++r)
                O[(size_t)(row + r) * DM + col] = acc[mi][ni][r] + bv;
        }
    }
}

// ---------------- RMSNorm + RoPE; Q additionally pre-scaled by 1/sqrt(128)*log2e ----------------
__global__ __launch_bounds__(256) void norm_rope(
    float* __restrict__ qf, float* __restrict__ kf, short* __restrict__ qbf,
    const float* __restrict__ gq, const float* __restrict__ gk,
    const float* __restrict__ freqs)
{
    const int buf = blockIdx.x >> 9;
    const int row = blockIdx.x & 511;
    const int t = threadIdx.x;
    float* src = buf ? kf : qf;
    const float* g = buf ? gk : gq;

    f32x2 v[6];
    float ss = 0.f;
    #pragma unroll
    for (int i = 0; i < 6; ++i) {
        int p = t + 256 * i;
        v[i] = *(const f32x2*)(src + (size_t)row * DM + 2 * p);
        ss += v[i][0] * v[i][0] + v[i][1] * v[i][1];
    }
    #pragma unroll
    for (int m = 1; m < 64; m <<= 1) ss += __shfl_xor(ss, m);
    __shared__ float red[4];
    if ((t & 63) == 0) red[t >> 6] = ss;
    __syncthreads();
    ss = red[0] + red[1] + red[2] + red[3];
    const float scale = rsqrtf(ss * (1.0f / DM) + 1e-6f);
    const float QS = 0.08838834764831845f * 1.4426950408889634f; // 1/sqrt(128)*log2e

    const int spos = row & 255;
    #pragma unroll
    for (int i = 0; i < 6; ++i) {
        int p = t + 256 * i;
        int d2 = p & 63;
        float fr = freqs[spos * 64 + d2];
        float sn, cs;
        __sincosf(fr, &sn, &cs);
        f32x2 gg = *(const f32x2*)(g + 2 * p);
        float re = v[i][0] * scale * gg[0];
        float im = v[i][1] * scale * gg[1];
        float re2 = re * cs - im * sn;
        float im2 = re * sn + im * cs;
        if (buf == 0) {
            re2 *= QS; im2 *= QS;
            unsigned pack = (unsigned)(unsigned short)bfc(re2)
                          | ((unsigned)(unsigned short)bfc(im2) << 16);
            *(unsigned*)(qbf + (size_t)row * DM + 2 * p) = pack;
        } else {
            f32x2 o; o[0] = re2; o[1] = im2;
            *(f32x2*)(src + (size_t)row * DM + 2 * p) = o;
        }
    }
}

// ---------------- Flash attention, swapped-QK^T (S^T = K*Q^T), P in-register ----------------
// grid 432 (XCD-grouped), 512 thr (8 waves); wave owns 32 q-cols; key tiles of 64.
// No P LDS buffer: P packed to bf16 in-reg, cross-group shfl exchange builds PV B-frags.
__global__ __launch_bounds__(512, 4) void attn_fa(
    const short* __restrict__ qbf, const float* __restrict__ kf, const float* __restrict__ vf,
    const float* __restrict__ kcache, const float* __restrict__ vcache,
    float* __restrict__ partO, float* __restrict__ partM, float* __restrict__ partL)
{
    const int bid = blockIdx.x;               // 0..431
    const int linear = (bid & 7) * 54 + (bid >> 3);
    const int c  = linear / 48;               // 0..8
    const int bh = linear % 48;
    const int b = bh / NH, h = bh % NH;
    const int t = threadIdx.x, lane = t & 63, wave = t >> 6;
    const int l15 = lane & 15, l4 = lane >> 4;
    const int hoff = h * HD;

    __shared__ short Ks[64][128];   // XOR-swizzled: byte ^= (row&7)<<4
    __shared__ short Vt[128][64];   // [d][kk], XOR-swizzled: byte ^= (d&7)<<4

    // Q B-fragments (n = q = l15)
    s16x8 qb[2][4];
    #pragma unroll
    for (int nj = 0; nj < 2; ++nj) {
        int qrow = b * SN + wave * 32 + nj * 16 + l15;
        #pragma unroll
        for (int kt = 0; kt < 4; ++kt)
            qb[nj][kt] = *(const s16x8*)(qbf + (size_t)qrow * DM + hoff + kt * 32 + l4 * 8);
    }

    f32x4 acc[2][8] = {};           // [nj][dfrag]: O^T, q=nj*16+l15, d=dfrag*16+l4*4+r
    float mrun[2] = {-INFINITY, -INFINITY}, lrun[2] = {0.f, 0.f};

    const int NT = (c < 8) ? 16 : 4;
    const float* ksrc; const float* vsrc; int row0;
    if (c < 8) { ksrc = kcache + (size_t)b * SCACHE * DM; vsrc = vcache + (size_t)b * SCACHE * DM; row0 = c * 1024; }
    else       { ksrc = kf + (size_t)b * SN * DM;         vsrc = vf + (size_t)b * SN * DM;         row0 = 0; }

    const int skk = t & 63, sdblk = t >> 6;   // V-stage coords
    f32x4 kreg[4], vreg[4];

    #pragma unroll
    for (int i = 0; i < 4; ++i) {
        int lin = i * 512 + t;
        kreg[i] = *(const f32x4*)(ksrc + (size_t)(row0 + (lin >> 5)) * DM + hoff + (lin & 31) * 4);
    }
    #pragma unroll
    for (int j = 0; j < 4; ++j)
        vreg[j] = *(const f32x4*)(vsrc + (size_t)(row0 + skk) * DM + hoff + sdblk * 16 + j * 4);

    const bool ghi = (l4 & 2) != 0;                 // g>>1
    const bool gin = (l4 == 0) || (l4 == 3);        // uses own/o16 halves

    for (int nt = 0; nt < NT; ++nt) {
        // ---- stage prefetched regs -> LDS (swizzled) ----
        #pragma unroll
        for (int i = 0; i < 4; ++i) {
            int lin = i * 512 + t;
            int row = lin >> 5;
            int kbyte = (row << 8) + (lin & 31) * 8;
            kbyte ^= (row & 7) << 4;
            s16x4 k4;
            #pragma unroll
            for (int j = 0; j < 4; ++j) k4[j] = bfc(kreg[i][j]);
            *(s16x4*)((char*)Ks + kbyte) = k4;
        }
        #pragma unroll
        for (int j = 0; j < 4; ++j) {
            #pragma unroll
            for (int jj = 0; jj < 4; ++jj) {
                int d = sdblk * 16 + j * 4 + jj;
                int vbyte = (d << 7) + skk * 2;
                vbyte ^= (d & 7) << 4;
                *(short*)((char*)Vt + vbyte) = bfc(vreg[j][jj]);
            }
        }
        __syncthreads();

        // ---- issue next-tile loads (fly across all compute below) ----
        if (nt + 1 < NT) {
            const int kr1 = row0 + (nt + 1) * 64;
            #pragma unroll
            for (int i = 0; i < 4; ++i) {
                int lin = i * 512 + t;
                kreg[i] = *(const f32x4*)(ksrc + (size_t)(kr1 + (lin >> 5)) * DM + hoff + (lin & 31) * 4);
            }
            #pragma unroll
            for (int j = 0; j < 4; ++j)
                vreg[j] = *(const f32x4*)(vsrc + (size_t)(kr1 + skk) * DM + hoff + sdblk * 16 + j * 4);
        }

        // ---- S^T = K * Q^T : st[mi][nj], k = mi*16+l4*4+r, q = nj*16+l15 ----
        f32x4 st[4][2] = {};
        #pragma unroll
        for (int kt = 0; kt < 4; ++kt)
            #pragma unroll
            for (int mi = 0; mi < 4; ++mi) {
                int kbyte = ((mi * 16 + l15) << 8) + kt * 64 + l4 * 16;
                kbyte ^= (l15 & 7) << 4;
                s16x8 kfr = *(const s16x8*)((const char*)Ks + kbyte);
                st[mi][0] = __builtin_amdgcn_mfma_f32_16x16x32_bf16(kfr, qb[0][kt], st[mi][0], 0, 0, 0);
                st[mi][1] = __builtin_amdgcn_mfma_f32_16x16x32_bf16(kfr, qb[1][kt], st[mi][1], 0, 0, 0);
            }

        // ---- online softmax: in-lane tree + 2 shfls per q-col ----
        float lm0 = fmaxf(
            fmaxf(fmaxf(fmaxf(st[0][0][0], st[0][0][1]), fmaxf(st[0][0][2], st[0][0][3])),
                  fmaxf(fmaxf(st[1][0][0], st[1][0][1]), fmaxf(st[1][0][2], st[1][0][3]))),
            fmaxf(fmaxf(fmaxf(st[2][0][0], st[2][0][1]), fmaxf(st[2][0][2], st[2][0][3])),
                  fmaxf(fmaxf(st[3][0][0], st[3][0][1]), fmaxf(st[3][0][2], st[3][0][3]))));
        float lm1 = fmaxf(
            fmaxf(fmaxf(fmaxf(st[0][1][0], st[0][1][1]), fmaxf(st[0][1][2], st[0][1][3])),
                  fmaxf(fmaxf(st[1][1][0], st[1][1][1]), fmaxf(st[1][1][2], st[1][1][3]))),
            fmaxf(fmaxf(fmaxf(st[2][1][0], st[2][1][1]), fmaxf(st[2][1][2], st[2][1][3])),
                  fmaxf(fmaxf(st[3][1][0], st[3][1][1]), fmaxf(st[3][1][2], st[3][1][3]))));
        lm0 = fmaxf(lm0, __shfl_xor(lm0, 16)); lm0 = fmaxf(lm0, __shfl_xor(lm0, 32));
        lm1 = fmaxf(lm1, __shfl_xor(lm1, 16)); lm1 = fmaxf(lm1, __shfl_xor(lm1, 32));

        // defer-max (T13): skip rescale when no row grew past mrun+8
        if (!__all((lm0 <= mrun[0] + 8.0f) && (lm1 <= mrun[1] + 8.0f))) {
            float mn0 = fmaxf(mrun[0], lm0), mn1 = fmaxf(mrun[1], lm1);
            float c0 = exp2f(mrun[0] - mn0), c1 = exp2f(mrun[1] - mn1);
            mrun[0] = mn0; mrun[1] = mn1;
            lrun[0] *= c0; lrun[1] *= c1;
            #pragma unroll
            for (int df = 0; df < 8; ++df) { acc[0][df] *= c0; acc[1][df] *= c1; }
        }

        float rs0 = 0.f, rs1 = 0.f;
        #pragma unroll
        for (int mi = 0; mi < 4; ++mi)
            #pragma unroll
            for (int r = 0; r < 4; ++r) {
                float p0 = exp2f(st[mi][0][r] - mrun[0]);
                float p1 = exp2f(st[mi][1][r] - mrun[1]);
                st[mi][0][r] = p0; st[mi][1][r] = p1;
                rs0 += p0; rs1 += p1;
            }
        rs0 += __shfl_xor(rs0, 16); rs0 += __shfl_xor(rs0, 32);
        rs1 += __shfl_xor(rs1, 16); rs1 += __shfl_xor(rs1, 32);
        lrun[0] += rs0; lrun[1] += rs1;

        // ---- pack P to bf16 pairs: up[nj][mi][i] holds k-pair mi*8+l4*2+i ----
        unsigned up[2][4][2];
        #pragma unroll
        for (int nj = 0; nj < 2; ++nj)
            #pragma unroll
            for (int mi = 0; mi < 4; ++mi)
                #pragma unroll
                for (int i = 0; i < 2; ++i)
                    up[nj][mi][i] = (unsigned)(unsigned short)bfc(st[mi][nj][2 * i])
                                  | ((unsigned)(unsigned short)bfc(st[mi][nj][2 * i + 1]) << 16);

        // ---- cross-group exchange -> PV B-frags bp[nj][kt2] (k = kt2*32+l4*8+j, n=q=l15) ----
        s16x8 bp[2][2];
        #pragma unroll
        for (int nj = 0; nj < 2; ++nj)
            #pragma unroll
            for (int kt2 = 0; kt2 < 2; ++kt2) {
                unsigned own0 = ghi ? up[nj][kt2 * 2 + 1][0] : up[nj][kt2 * 2 + 0][0];
                unsigned own1 = ghi ? up[nj][kt2 * 2 + 1][1] : up[nj][kt2 * 2 + 0][1];
                unsigned alt0 = ghi ? up[nj][kt2 * 2 + 0][0] : up[nj][kt2 * 2 + 1][0];
                unsigned alt1 = ghi ? up[nj][kt2 * 2 + 0][1] : up[nj][kt2 * 2 + 1][1];
                unsigned o16_0 = __shfl_xor(own0, 16), o16_1 = __shfl_xor(own1, 16);
                unsigned o32_0 = __shfl_xor(alt0, 32), o32_1 = __shfl_xor(alt1, 32);
                unsigned o48_0 = __shfl_xor(alt0, 48), o48_1 = __shfl_xor(alt1, 48);
                u32x4 uu;
                uu[0] = gin ? (ghi ? o16_0 : own0) : (ghi ? o32_0 : o48_0);
                uu[1] = gin ? (ghi ? o16_1 : own1) : (ghi ? o32_1 : o48_1);
                uu[2] = gin ? (ghi ? own0 : o16_0) : (ghi ? o48_0 : o32_0);
                uu[3] = gin ? (ghi ? own1 : o16_1) : (ghi ? o48_1 : o32_1);
                bp[nj][kt2] = __builtin_bit_cast(s16x8, uu);
            }

        // ---- PV: acc[nj][df] += V^T-frag * bp ----
        #pragma unroll
        for (int kt2 = 0; kt2 < 2; ++kt2)
            #pragma unroll
            for (int df = 0; df < 8; ++df) {
                int vbyte = ((df * 16 + l15) << 7) + kt2 * 64 + l4 * 16;
                vbyte ^= (l15 & 7) << 4;
                s16x8 vfr = *(const s16x8*)((const char*)Vt + vbyte);
                acc[0][df] = __builtin_amdgcn_mfma_f32_16x16x32_bf16(vfr, bp[0][kt2], acc[0][df], 0, 0, 0);
                acc[1][df] = __builtin_amdgcn_mfma_f32_16x16x32_bf16(vfr, bp[1][kt2], acc[1][df], 0, 0, 0);
            }
        __syncthreads();
    }

    // ---- write partials (c innermost; f32x4 stores) ----
    #pragma unroll
    for (int nj = 0; nj < 2; ++nj) {
        size_t rowid = (size_t)bh * SN + wave * 32 + nj * 16 + l15;
        float* po = partO + (rowid * NCH + c) * HD + l4 * 4;
        #pragma unroll
        for (int df = 0; df < 8; ++df)
            *(f32x4*)(po + df * 16) = acc[nj][df];
        if (l4 == 0) {
            partM[rowid * NCH + c] = mrun[nj];
            partL[rowid * NCH + c] = lrun[nj];
        }
    }
}

// ---------------- combine split-K partials (contiguous per-row reads) ----------------
__global__ __launch_bounds__(128) void combine(
    const float* __restrict__ partO, const float* __restrict__ partM,
    const float* __restrict__ partL, float* __restrict__ attn)
{
    const int rowid = blockIdx.x;        // bh*256 + q
    const int bh = rowid >> 8, q = rowid & 255;
    const int b = bh / NH, h = bh % NH;
    const int d = threadIdx.x;

    float m[NCH];
    float M = -INFINITY;
    #pragma unroll
    for (int c = 0; c < NCH; ++c) { m[c] = partM[(size_t)rowid * NCH + c]; M = fmaxf(M, m[c]); }
    float L = 0.f, o = 0.f;
    #pragma unroll
    for (int c = 0; c < NCH; ++c) {
        float w = exp2f(m[c] - M);
        L += partL[(size_t)rowid * NCH + c] * w;
        o += partO[((size_t)rowid * NCH + c) * HD + d] * w;
    }
    attn[(size_t)(b * SN + q) * DM + h * HD + d] = o / L;
}

extern "C" void kernel_launch(void* const* d_in, const int* in_sizes, int n_in,
                              void* d_out, int out_size, void* d_ws, size_t ws_size,
                              hipStream_t stream) {
    const float* x      = (const float*)d_in[0];
    const float* freqs  = (const float*)d_in[1];
    const float* kcache = (const float*)d_in[2];
    const float* vcache = (const float*)d_in[3];
    const float* Wq = (const float*)d_in[4];
    const float* bq = (const float*)d_in[5];
    const float* Wk = (const float*)d_in[6];
    const float* bk = (const float*)d_in[7];
    const float* Wv = (const float*)d_in[8];
    const float* bv = (const float*)d_in[9];
    const float* Wo = (const float*)d_in[10];
    const float* bo = (const float*)d_in[11];
    const float* gq = (const float*)d_in[12];
    const float* gk = (const float*)d_in[13];
    float* out = (float*)d_out;

    char* ws = (char*)d_ws;
    float* qf   = (float*)ws; ws += (size_t)MR * DM * 4;
    float* kfb  = (float*)ws; ws += (size_t)MR * DM * 4;
    float* vfb  = (float*)ws; ws += (size_t)MR * DM * 4;
    short* qbf  = (short*)ws; ws += (size_t)MR * DM * 2;
    float* pO   = (float*)ws; ws += (size_t)NCH * 48 * SN * HD * 4;
    float* pM   = (float*)ws; ws += (size_t)NCH * 48 * SN * 4;
    float* pL   = (float*)ws; ws += (size_t)NCH * 48 * SN * 4;
    float* attn = (float*)ws; ws += (size_t)MR * DM * 4;

    gemm_bias<<<dim3(24, 8, 3), 256, 0, stream>>>(x, Wq, Wk, Wv, bq, bk, bv, qf, kfb, vfb);
    norm_rope<<<dim3(1024), 256, 0, stream>>>(qf, kfb, qbf, gq, gk, freqs);
    attn_fa<<<dim3(432), 512, 0, stream>>>(qbf, kfb, vfb, kcache, vcache, pO, pM, pL);
    combine<<<dim3(12288), 128, 0, stream>>>(pO, pM, pL, attn);
    gemm_bias<<<dim3(24, 8, 1), 256, 0, stream>>>(attn, Wo, Wo, Wo, bo, bo, bo, out, out, out);
}

// Round 6
// 429.017 us; speedup vs baseline: 1.6099x; 1.6099x over previous
//
#include <hip/hip_runtime.h>
#include <hip/hip_bf16.h>

#define NH 24
#define HD 128
#define DM 3072
#define NB 2
#define SN 256
#define MR 512            // NB*SN rows
#define SCACHE 8192
#define STOT 8448         // 8192 cached + 256 new

typedef float f32x4 __attribute__((ext_vector_type(4)));
typedef float f32x2 __attribute__((ext_vector_type(2)));
typedef short s16x8 __attribute__((ext_vector_type(8)));
typedef short s16x4 __attribute__((ext_vector_type(4)));
typedef unsigned u32x4 __attribute__((ext_vector_type(4)));

__device__ __forceinline__ short bfc(float f) {
    __hip_bfloat16 h = __float2bfloat16(f);
    return __builtin_bit_cast(short, h);
}

// ---------------- GEMM: O[m,n] = sum_k A[m,k]*W[n,k] + bias[n] ----------------
__global__ __launch_bounds__(256, 3) void gemm_bias(
    const float* __restrict__ A,
    const float* __restrict__ W0, const float* __restrict__ W1, const float* __restrict__ W2,
    const float* __restrict__ b0, const float* __restrict__ b1, const float* __restrict__ b2,
    float* __restrict__ O0, float* __restrict__ O1, float* __restrict__ O2)
{
    const int z = blockIdx.z;
    const float* W    = (z == 0) ? W0 : (z == 1) ? W1 : W2;
    const float* bias = (z == 0) ? b0 : (z == 1) ? b1 : b2;
    float* O          = (z == 0) ? O0 : (z == 1) ? O1 : O2;

    const int n0 = blockIdx.x * 128;
    const int m0 = blockIdx.y * 64;
    const int t = threadIdx.x;
    const int lane = t & 63;
    const int wave = t >> 6;
    const int l15 = lane & 15, l4 = lane >> 4;
    const int wm = (wave >> 1) * 32, wn = (wave & 1) * 64;

    __shared__ short As[64][72];
    __shared__ short Bs[128][72];

    f32x4 acc[2][4] = {};
    f32x4 areg[4], breg[8];

    #pragma unroll
    for (int i = 0; i < 4; ++i) {
        int lin = i * 256 + t;
        areg[i] = *(const f32x4*)(A + (size_t)(m0 + (lin >> 4)) * DM + (lin & 15) * 4);
    }
    #pragma unroll
    for (int i = 0; i < 8; ++i) {
        int lin = i * 256 + t;
        breg[i] = *(const f32x4*)(W + (size_t)(n0 + (lin >> 4)) * DM + (lin & 15) * 4);
    }

    for (int ks = 0; ks < DM / 64; ++ks) {
        #pragma unroll
        for (int i = 0; i < 4; ++i) {
            int lin = i * 256 + t;
            s16x4 a4;
            #pragma unroll
            for (int j = 0; j < 4; ++j) a4[j] = bfc(areg[i][j]);
            *(s16x4*)&As[lin >> 4][(lin & 15) * 4] = a4;
        }
        #pragma unroll
        for (int i = 0; i < 8; ++i) {
            int lin = i * 256 + t;
            s16x4 w4;
            #pragma unroll
            for (int j = 0; j < 4; ++j) w4[j] = bfc(breg[i][j]);
            *(s16x4*)&Bs[lin >> 4][(lin & 15) * 4] = w4;
        }
        __syncthreads();
        if (ks + 1 < DM / 64) {
            int k0 = (ks + 1) * 64;
            #pragma unroll
            for (int i = 0; i < 4; ++i) {
                int lin = i * 256 + t;
                areg[i] = *(const f32x4*)(A + (size_t)(m0 + (lin >> 4)) * DM + k0 + (lin & 15) * 4);
            }
            #pragma unroll
            for (int i = 0; i < 8; ++i) {
                int lin = i * 256 + t;
                breg[i] = *(const f32x4*)(W + (size_t)(n0 + (lin >> 4)) * DM + k0 + (lin & 15) * 4);
            }
        }
        #pragma unroll
        for (int kt = 0; kt < 2; ++kt) {
            s16x8 af[2], bfr[4];
            #pragma unroll
            for (int i = 0; i < 2; ++i)
                af[i]  = *(const s16x8*)&As[wm + i * 16 + l15][kt * 32 + l4 * 8];
            #pragma unroll
            for (int i = 0; i < 4; ++i)
                bfr[i] = *(const s16x8*)&Bs[wn + i * 16 + l15][kt * 32 + l4 * 8];
            #pragma unroll
            for (int mi = 0; mi < 2; ++mi)
                #pragma unroll
                for (int ni = 0; ni < 4; ++ni)
                    acc[mi][ni] = __builtin_amdgcn_mfma_f32_16x16x32_bf16(
                        af[mi], bfr[ni], acc[mi][ni], 0, 0, 0);
        }
        __syncthreads();
    }

    #pragma unroll
    for (int ni = 0; ni < 4; ++ni) {
        int col = n0 + wn + ni * 16 + l15;
        float bv = bias[col];
        #pragma unroll
        for (int mi = 0; mi < 2; ++mi) {
            int row = m0 + wm + mi * 16 + l4 * 4;
            #pragma unroll
            for (int r = 0; r < 4; ++r)
                O[(size_t)(row + r) * DM + col] = acc[mi][ni][r] + bv;
        }
    }
}

// ---------------- cache repack: fp32 [b][s][h*128] -> bf16 head-major [b][h][s][128] ----------------
// Pure streaming reads; 256B-chunk writes. Doubles as a streaming-BW probe.
__global__ __launch_bounds__(256) void repack(
    const float* __restrict__ kcache, const float* __restrict__ vcache,
    short* __restrict__ khm, short* __restrict__ vhm)
{
    const int s = blockIdx.x;           // 0..8191
    const int b = blockIdx.y;           // 0..1
    const int kv = blockIdx.z;          // 0=K 1=V
    const float* src = (kv ? vcache : kcache) + ((size_t)b * SCACHE + s) * DM;
    short* dst = kv ? vhm : khm;
    const int t = threadIdx.x;
    #pragma unroll
    for (int i = 0; i < 3; ++i) {
        int p = t + 256 * i;            // 0..767 f32x4 chunks
        f32x4 v = *(const f32x4*)(src + p * 4);
        int h = p >> 5, d4 = p & 31;
        s16x4 o;
        #pragma unroll
        for (int j = 0; j < 4; ++j) o[j] = bfc(v[j]);
        *(s16x4*)(dst + ((size_t)(b * NH + h) * STOT + s) * HD + d4 * 4) = o;
    }
}

// ---------------- RMSNorm + RoPE (+ head-major bf16 outputs for new K/V) ----------------
// grid x: hm ? 1536 : 1024. buf = blockIdx>>9: 0=Q, 1=K, 2=V-passthrough(hm only)
__global__ __launch_bounds__(256) void norm_rope(
    float* __restrict__ qf, float* __restrict__ kf, const float* __restrict__ vf,
    short* __restrict__ qbf,
    const float* __restrict__ gq, const float* __restrict__ gk,
    const float* __restrict__ freqs,
    short* __restrict__ khm, short* __restrict__ vhm, int hm)
{
    const int buf = blockIdx.x >> 9;
    const int row = blockIdx.x & 511;
    const int b = row >> 8, sn = row & 255;
    const int t = threadIdx.x;

    if (buf == 2) {   // new V -> vhm (no norm, no rope)
        #pragma unroll
        for (int i = 0; i < 6; ++i) {
            int p = t + 256 * i;           // pair index 0..1535
            f32x2 v = *(const f32x2*)(vf + (size_t)row * DM + 2 * p);
            int h = p >> 6, dp = p & 63;
            unsigned pack = (unsigned)(unsigned short)bfc(v[0])
                          | ((unsigned)(unsigned short)bfc(v[1]) << 16);
            *(unsigned*)(vhm + ((size_t)(b * NH + h) * STOT + SCACHE + sn) * HD + dp * 2) = pack;
        }
        return;
    }

    float* src = buf ? kf : qf;
    const float* g = buf ? gk : gq;

    f32x2 v[6];
    float ss = 0.f;
    #pragma unroll
    for (int i = 0; i < 6; ++i) {
        int p = t + 256 * i;
        v[i] = *(const f32x2*)(src + (size_t)row * DM + 2 * p);
        ss += v[i][0] * v[i][0] + v[i][1] * v[i][1];
    }
    #pragma unroll
    for (int m = 1; m < 64; m <<= 1) ss += __shfl_xor(ss, m);
    __shared__ float red[4];
    if ((t & 63) == 0) red[t >> 6] = ss;
    __syncthreads();
    ss = red[0] + red[1] + red[2] + red[3];
    const float scale = rsqrtf(ss * (1.0f / DM) + 1e-6f);
    const float QS = 0.08838834764831845f * 1.4426950408889634f; // 1/sqrt(128)*log2e

    #pragma unroll
    for (int i = 0; i < 6; ++i) {
        int p = t + 256 * i;
        int d2 = p & 63;
        float fr = freqs[sn * 64 + d2];
        float snv, cs;
        __sincosf(fr, &snv, &cs);
        f32x2 gg = *(const f32x2*)(g + 2 * p);
        float re = v[i][0] * scale * gg[0];
        float im = v[i][1] * scale * gg[1];
        float re2 = re * cs - im * snv;
        float im2 = re * snv + im * cs;
        if (buf == 0) {
            re2 *= QS; im2 *= QS;
            unsigned pack = (unsigned)(unsigned short)bfc(re2)
                          | ((unsigned)(unsigned short)bfc(im2) << 16);
            *(unsigned*)(qbf + (size_t)row * DM + 2 * p) = pack;
        } else if (hm) {
            int h = p >> 6, dp = p & 63;
            unsigned pack = (unsigned)(unsigned short)bfc(re2)
                          | ((unsigned)(unsigned short)bfc(im2) << 16);
            *(unsigned*)(khm + ((size_t)(b * NH + h) * STOT + SCACHE + sn) * HD + dp * 2) = pack;
        } else {
            f32x2 o; o[0] = re2; o[1] = im2;
            *(f32x2*)(src + (size_t)row * DM + 2 * p) = o;
        }
    }
}

// ---------------- Flash attention, swapped-QK^T, P in-register ----------------
// HM=true : bf16 head-major sources, 11 uniform chunks of 768 keys (grid 528).
// HM=false: fp32 row-major sources, 9 chunks (8x1024 cache + 256 new, grid 432).
// LDS chunk-XOR swizzle: 16B-chunk index ^= (row & mask) on both stage and read.
template<bool HM>
__global__ __launch_bounds__(512) void attn_fa(
    const short* __restrict__ qbf,
    const short* __restrict__ khm, const short* __restrict__ vhm,
    const float* __restrict__ kf, const float* __restrict__ vf,
    const float* __restrict__ kcache, const float* __restrict__ vcache,
    float* __restrict__ partO, float* __restrict__ partM, float* __restrict__ partL)
{
    constexpr int NCHt = HM ? 11 : 9;
    const int bid = blockIdx.x;
    const int linear = HM ? bid : ((bid & 7) * 54 + (bid >> 3));
    const int c  = linear / 48;
    const int bh = linear % 48;
    const int b = bh / NH, h = bh % NH;
    const int t = threadIdx.x, lane = t & 63, wave = t >> 6;
    const int l15 = lane & 15, l4 = lane >> 4;
    const int hoff = h * HD;

    __shared__ short Ks[64 * 128];   // [k][d] 256B rows, chunk-swizzled
    __shared__ short Vt[128 * 64];   // [d][k] 128B rows, chunk-swizzled
    char* KsB = (char*)Ks;
    char* VtB = (char*)Vt;

    s16x8 qb[2][4];
    #pragma unroll
    for (int nj = 0; nj < 2; ++nj) {
        int qrow = b * SN + wave * 32 + nj * 16 + l15;
        #pragma unroll
        for (int kt = 0; kt < 4; ++kt)
            qb[nj][kt] = *(const s16x8*)(qbf + (size_t)qrow * DM + hoff + kt * 32 + l4 * 8);
    }

    f32x4 acc[2][8] = {};
    float mrun[2] = {-INFINITY, -INFINITY}, lrun[2] = {0.f, 0.f};

    int NT;
    const short* khsrc = nullptr; const short* vhsrc = nullptr;
    const float* ksrc = nullptr; const float* vsrc = nullptr; int row0 = 0;
    if constexpr (HM) {
        NT = 12;
        khsrc = khm + ((size_t)(b * NH + h) * STOT + c * 768) * HD;
        vhsrc = vhm + ((size_t)(b * NH + h) * STOT + c * 768) * HD;
    } else {
        NT = (c < 8) ? 16 : 4;
        if (c < 8) { ksrc = kcache + (size_t)b * SCACHE * DM; vsrc = vcache + (size_t)b * SCACHE * DM; row0 = c * 1024; }
        else       { ksrc = kf + (size_t)b * SN * DM;         vsrc = vf + (size_t)b * SN * DM;         row0 = 0; }
    }

    // prefetch registers (per-variant; unused set is DCE'd)
    s16x8 kreg2[2], vreg2[2];
    f32x4 kreg[4], vreg[4];
    const int vrow = t & 63, vw = t >> 6;       // V-stage coords (both variants)

    if constexpr (HM) {
        #pragma unroll
        for (int i = 0; i < 2; ++i) {
            int lin = i * 512 + t;
            kreg2[i] = *(const s16x8*)(khsrc + (size_t)(lin >> 4) * HD + (lin & 15) * 8);
            vreg2[i] = *(const s16x8*)(vhsrc + (size_t)vrow * HD + vw * 16 + i * 8);
        }
    } else {
        #pragma unroll
        for (int i = 0; i < 4; ++i) {
            int lin = i * 512 + t;
            kreg[i] = *(const f32x4*)(ksrc + (size_t)(row0 + (lin >> 5)) * DM + hoff + (lin & 31) * 4);
        }
        #pragma unroll
        for (int j = 0; j < 4; ++j)
            vreg[j] = *(const f32x4*)(vsrc + (size_t)(row0 + vrow) * DM + hoff + vw * 16 + j * 4);
    }

    const bool ghi = (l4 & 2) != 0;
    const bool gin = (l4 == 0) || (l4 == 3);

    for (int nt = 0; nt < NT; ++nt) {
        // ---- stage prefetched regs -> LDS (chunk-swizzled) ----
        if constexpr (HM) {
            #pragma unroll
            for (int i = 0; i < 2; ++i) {
                int lin = i * 512 + t;
                int row = lin >> 4, col8 = lin & 15;
                *(s16x8*)(KsB + (row << 8) + ((col8 ^ (row & 15)) << 4)) = kreg2[i];   // FIX: & 15
                #pragma unroll
                for (int j = 0; j < 8; ++j) {
                    int d = vw * 16 + i * 8 + j;
                    *(short*)(VtB + (d << 7) + ((((vrow >> 3) ^ (d & 7))) << 4) + ((vrow & 7) << 1)) = vreg2[i][j];
                }
            }
        } else {
            #pragma unroll
            for (int i = 0; i < 4; ++i) {
                int lin = i * 512 + t;
                int row = lin >> 5, col4 = lin & 31;
                s16x4 k4;
                #pragma unroll
                for (int j = 0; j < 4; ++j) k4[j] = bfc(kreg[i][j]);
                *(s16x4*)(KsB + (row << 8) + ((((col4 >> 1) ^ row) & 15) << 4) + ((col4 & 1) << 3)) = k4;
            }
            #pragma unroll
            for (int j = 0; j < 4; ++j) {
                #pragma unroll
                for (int jj = 0; jj < 4; ++jj) {
                    int d = vw * 16 + j * 4 + jj;
                    *(short*)(VtB + (d << 7) + ((((vrow >> 3) ^ (d & 7))) << 4) + ((vrow & 7) << 1)) = bfc(vreg[j][jj]);
                }
            }
        }
        __syncthreads();

        // ---- issue next-tile loads ----
        if (nt + 1 < NT) {
            if constexpr (HM) {
                const short* kh1 = khsrc + (size_t)(nt + 1) * 64 * HD;
                const short* vh1 = vhsrc + (size_t)(nt + 1) * 64 * HD;
                #pragma unroll
                for (int i = 0; i < 2; ++i) {
                    int lin = i * 512 + t;
                    kreg2[i] = *(const s16x8*)(kh1 + (size_t)(lin >> 4) * HD + (lin & 15) * 8);
                    vreg2[i] = *(const s16x8*)(vh1 + (size_t)vrow * HD + vw * 16 + i * 8);
                }
            } else {
                const int kr1 = row0 + (nt + 1) * 64;
                #pragma unroll
                for (int i = 0; i < 4; ++i) {
                    int lin = i * 512 + t;
                    kreg[i] = *(const f32x4*)(ksrc + (size_t)(kr1 + (lin >> 5)) * DM + hoff + (lin & 31) * 4);
                }
                #pragma unroll
                for (int j = 0; j < 4; ++j)
                    vreg[j] = *(const f32x4*)(vsrc + (size_t)(kr1 + vrow) * DM + hoff + vw * 16 + j * 4);
            }
        }

        // ---- S^T = K * Q^T ----
        f32x4 st[4][2] = {};
        #pragma unroll
        for (int kt = 0; kt < 4; ++kt)
            #pragma unroll
            for (int mi = 0; mi < 4; ++mi) {
                int row = mi * 16 + l15;
                s16x8 kfr = *(const s16x8*)(KsB + (row << 8) + (((kt * 4 + l4) ^ l15) << 4));
                st[mi][0] = __builtin_amdgcn_mfma_f32_16x16x32_bf16(kfr, qb[0][kt], st[mi][0], 0, 0, 0);
                st[mi][1] = __builtin_amdgcn_mfma_f32_16x16x32_bf16(kfr, qb[1][kt], st[mi][1], 0, 0, 0);
            }

        // ---- online softmax ----
        float lm0 = fmaxf(
            fmaxf(fmaxf(fmaxf(st[0][0][0], st[0][0][1]), fmaxf(st[0][0][2], st[0][0][3])),
                  fmaxf(fmaxf(st[1][0][0], st[1][0][1]), fmaxf(st[1][0][2], st[1][0][3]))),
            fmaxf(fmaxf(fmaxf(st[2][0][0], st[2][0][1]), fmaxf(st[2][0][2], st[2][0][3])),
                  fmaxf(fmaxf(st[3][0][0], st[3][0][1]), fmaxf(st[3][0][2], st[3][0][3]))));
        float lm1 = fmaxf(
            fmaxf(fmaxf(fmaxf(st[0][1][0], st[0][1][1]), fmaxf(st[0][1][2], st[0][1][3])),
                  fmaxf(fmaxf(st[1][1][0], st[1][1][1]), fmaxf(st[1][1][2], st[1][1][3]))),
            fmaxf(fmaxf(fmaxf(st[2][1][0], st[2][1][1]), fmaxf(st[2][1][2], st[2][1][3])),
                  fmaxf(fmaxf(st[3][1][0], st[3][1][1]), fmaxf(st[3][1][2], st[3][1][3]))));
        lm0 = fmaxf(lm0, __shfl_xor(lm0, 16)); lm0 = fmaxf(lm0, __shfl_xor(lm0, 32));
        lm1 = fmaxf(lm1, __shfl_xor(lm1, 16)); lm1 = fmaxf(lm1, __shfl_xor(lm1, 32));

        if (!__all((lm0 <= mrun[0] + 8.0f) && (lm1 <= mrun[1] + 8.0f))) {
            float mn0 = fmaxf(mrun[0], lm0), mn1 = fmaxf(mrun[1], lm1);
            float c0 = exp2f(mrun[0] - mn0), c1 = exp2f(mrun[1] - mn1);
            mrun[0] = mn0; mrun[1] = mn1;
            lrun[0] *= c0; lrun[1] *= c1;
            #pragma unroll
            for (int df = 0; df < 8; ++df) { acc[0][df] *= c0; acc[1][df] *= c1; }
        }

        float rs0 = 0.f, rs1 = 0.f;
        #pragma unroll
        for (int mi = 0; mi < 4; ++mi)
            #pragma unroll
            for (int r = 0; r < 4; ++r) {
                float p0 = exp2f(st[mi][0][r] - mrun[0]);
                float p1 = exp2f(st[mi][1][r] - mrun[1]);
                st[mi][0][r] = p0; st[mi][1][r] = p1;
                rs0 += p0; rs1 += p1;
            }
        rs0 += __shfl_xor(rs0, 16); rs0 += __shfl_xor(rs0, 32);
        rs1 += __shfl_xor(rs1, 16); rs1 += __shfl_xor(rs1, 32);
        lrun[0] += rs0; lrun[1] += rs1;

        // ---- pack P to bf16 pairs ----
        unsigned up[2][4][2];
        #pragma unroll
        for (int nj = 0; nj < 2; ++nj)
            #pragma unroll
            for (int mi = 0; mi < 4; ++mi)
                #pragma unroll
                for (int i = 0; i < 2; ++i)
                    up[nj][mi][i] = (unsigned)(unsigned short)bfc(st[mi][nj][2 * i])
                                  | ((unsigned)(unsigned short)bfc(st[mi][nj][2 * i + 1]) << 16);

        // ---- cross-group exchange -> PV B-frags ----
        s16x8 bp[2][2];
        #pragma unroll
        for (int nj = 0; nj < 2; ++nj)
            #pragma unroll
            for (int kt2 = 0; kt2 < 2; ++kt2) {
                unsigned own0 = ghi ? up[nj][kt2 * 2 + 1][0] : up[nj][kt2 * 2 + 0][0];
                unsigned own1 = ghi ? up[nj][kt2 * 2 + 1][1] : up[nj][kt2 * 2 + 0][1];
                unsigned alt0 = ghi ? up[nj][kt2 * 2 + 0][0] : up[nj][kt2 * 2 + 1][0];
                unsigned alt1 = ghi ? up[nj][kt2 * 2 + 0][1] : up[nj][kt2 * 2 + 1][1];
                unsigned o16_0 = __shfl_xor(own0, 16), o16_1 = __shfl_xor(own1, 16);
                unsigned o32_0 = __shfl_xor(alt0, 32), o32_1 = __shfl_xor(alt1, 32);
                unsigned o48_0 = __shfl_xor(alt0, 48), o48_1 = __shfl_xor(alt1, 48);
                u32x4 uu;
                uu[0] = gin ? (ghi ? o16_0 : own0) : (ghi ? o32_0 : o48_0);
                uu[1] = gin ? (ghi ? o16_1 : own1) : (ghi ? o32_1 : o48_1);
                uu[2] = gin ? (ghi ? own0 : o16_0) : (ghi ? o48_0 : o32_0);
                uu[3] = gin ? (ghi ? own1 : o16_1) : (ghi ? o48_1 : o32_1);
                bp[nj][kt2] = __builtin_bit_cast(s16x8, uu);
            }

        // ---- PV ----
        #pragma unroll
        for (int kt2 = 0; kt2 < 2; ++kt2)
            #pragma unroll
            for (int df = 0; df < 8; ++df) {
                int row = df * 16 + l15;
                s16x8 vfr = *(const s16x8*)(VtB + (row << 7) + (((kt2 * 4 + l4) ^ (row & 7)) << 4));
                acc[0][df] = __builtin_amdgcn_mfma_f32_16x16x32_bf16(vfr, bp[0][kt2], acc[0][df], 0, 0, 0);
                acc[1][df] = __builtin_amdgcn_mfma_f32_16x16x32_bf16(vfr, bp[1][kt2], acc[1][df], 0, 0, 0);
            }
        __syncthreads();
    }

    // ---- write partials ----
    #pragma unroll
    for (int nj = 0; nj < 2; ++nj) {
        size_t rowid = (size_t)bh * SN + wave * 32 + nj * 16 + l15;
        float* po = partO + (rowid * NCHt + c) * HD + l4 * 4;
        #pragma unroll
        for (int df = 0; df < 8; ++df)
            *(f32x4*)(po + df * 16) = acc[nj][df];
        if (l4 == 0) {
            partM[rowid * NCHt + c] = mrun[nj];
            partL[rowid * NCHt + c] = lrun[nj];
        }
    }
}

// ---------------- combine split-K partials ----------------
template<int NCHt>
__global__ __launch_bounds__(128) void combine(
    const float* __restrict__ partO, const float* __restrict__ partM,
    const float* __restrict__ partL, float* __restrict__ attn)
{
    const int rowid = blockIdx.x;        // bh*256 + q
    const int bh = rowid >> 8, q = rowid & 255;
    const int b = bh / NH, h = bh % NH;
    const int d = threadIdx.x;

    float m[NCHt];
    float M = -INFINITY;
    #pragma unroll
    for (int c = 0; c < NCHt; ++c) { m[c] = partM[(size_t)rowid * NCHt + c]; M = fmaxf(M, m[c]); }
    float L = 0.f, o = 0.f;
    #pragma unroll
    for (int c = 0; c < NCHt; ++c) {
        float w = exp2f(m[c] - M);
        L += partL[(size_t)rowid * NCHt + c] * w;
        o += partO[((size_t)rowid * NCHt + c) * HD + d] * w;
    }
    attn[(size_t)(b * SN + q) * DM + h * HD + d] = o / L;
}

extern "C" void kernel_launch(void* const* d_in, const int* in_sizes, int n_in,
                              void* d_out, int out_size, void* d_ws, size_t ws_size,
                              hipStream_t stream) {
    const float* x      = (const float*)d_in[0];
    const float* freqs  = (const float*)d_in[1];
    const float* kcache = (const float*)d_in[2];
    const float* vcache = (const float*)d_in[3];
    const float* Wq = (const float*)d_in[4];
    const float* bq = (const float*)d_in[5];
    const float* Wk = (const float*)d_in[6];
    const float* bk = (const float*)d_in[7];
    const float* Wv = (const float*)d_in[8];
    const float* bv = (const float*)d_in[9];
    const float* Wo = (const float*)d_in[10];
    const float* bo = (const float*)d_in[11];
    const float* gq = (const float*)d_in[12];
    const float* gk = (const float*)d_in[13];
    float* out = (float*)d_out;

    // ws layout (256B-aligned chunks)
    const size_t SZ_QF  = (size_t)MR * DM * 4;           // 6.29 MB
    const size_t SZ_QBF = (size_t)MR * DM * 2;           // 3.15 MB
    const size_t SZ_PML = (size_t)48 * SN * 11 * 4;      // 0.54 MB (sized for max NCH)
    const size_t SZ_HM  = (size_t)NB * NH * STOT * HD * 2; // 103.8 MB
    const size_t SZ_PO11 = (size_t)48 * SN * 11 * HD * 4;  // 69.2 MB
    const size_t SZ_PO9  = (size_t)48 * SN * 9 * HD * 4;   // 56.6 MB
    auto al = [](size_t v) { return (v + 255) & ~(size_t)255; };

    const size_t base = al(SZ_QF) * 3 + al(SZ_QBF) + al(SZ_PML) * 2 + al(SZ_QF); // qf,kfb,vfb,qbf,pM,pL,attn
    const size_t need_hm = base + al(SZ_PO11) + al(SZ_HM) * 2;
    const bool hm = ws_size >= need_hm;

    char* ws = (char*)d_ws;
    float* qf   = (float*)ws; ws += al(SZ_QF);
    float* kfb  = (float*)ws; ws += al(SZ_QF);
    float* vfb  = (float*)ws; ws += al(SZ_QF);
    short* qbf  = (short*)ws; ws += al(SZ_QBF);
    float* pM   = (float*)ws; ws += al(SZ_PML);
    float* pL   = (float*)ws; ws += al(SZ_PML);
    float* attn = (float*)ws; ws += al(SZ_QF);
    float* pO   = (float*)ws; ws += al(hm ? SZ_PO11 : SZ_PO9);
    short* khm  = (short*)ws; ws += al(SZ_HM);
    short* vhm  = (short*)ws; ws += al(SZ_HM);

    if (hm)
        repack<<<dim3(SCACHE, NB, 2), 256, 0, stream>>>(kcache, vcache, khm, vhm);

    gemm_bias<<<dim3(24, 8, 3), 256, 0, stream>>>(x, Wq, Wk, Wv, bq, bk, bv, qf, kfb, vfb);
    norm_rope<<<dim3(hm ? 1536 : 1024), 256, 0, stream>>>(qf, kfb, vfb, qbf, gq, gk, freqs, khm, vhm, hm ? 1 : 0);

    if (hm) {
        attn_fa<true><<<dim3(528), 512, 0, stream>>>(qbf, khm, vhm, nullptr, nullptr, nullptr, nullptr, pO, pM, pL);
        combine<11><<<dim3(12288), 128, 0, stream>>>(pO, pM, pL, attn);
    } else {
        attn_fa<false><<<dim3(432), 512, 0, stream>>>(qbf, nullptr, nullptr, kfb, vfb, kcache, vcache, pO, pM, pL);
        combine<9><<<dim3(12288), 128, 0, stream>>>(pO, pM, pL, attn);
    }

    gemm_bias<<<dim3(24, 8, 1), 256, 0, stream>>>(attn, Wo, Wo, Wo, bo, bo, bo, out, out, out);
}

// Round 7
// 312.372 us; speedup vs baseline: 2.2110x; 1.3734x over previous
//
#include <hip/hip_runtime.h>
#include <hip/hip_bf16.h>

#define NH 24
#define HD 128
#define DM 3072
#define NB 2
#define SN 256
#define MR 512            // NB*SN rows
#define SCACHE 8192
#define NCH 9             // 6 chunks of 15 tiles + 3 of 14 tiles (132 tiles of 64 keys)

typedef float f32x4 __attribute__((ext_vector_type(4)));
typedef float f32x2 __attribute__((ext_vector_type(2)));
typedef short s16x8 __attribute__((ext_vector_type(8)));
typedef short s16x4 __attribute__((ext_vector_type(4)));
typedef unsigned u32x4 __attribute__((ext_vector_type(4)));

__device__ __forceinline__ short bfc(float f) {
    __hip_bfloat16 h = __float2bfloat16(f);
    return __builtin_bit_cast(short, h);
}

// ---------------- GEMM: O[m,n] = sum_k A[m,k]*W[n,k] + bias[n] ----------------
__global__ __launch_bounds__(256, 3) void gemm_bias(
    const float* __restrict__ A,
    const float* __restrict__ W0, const float* __restrict__ W1, const float* __restrict__ W2,
    const float* __restrict__ b0, const float* __restrict__ b1, const float* __restrict__ b2,
    float* __restrict__ O0, float* __restrict__ O1, float* __restrict__ O2)
{
    const int z = blockIdx.z;
    const float* W    = (z == 0) ? W0 : (z == 1) ? W1 : W2;
    const float* bias = (z == 0) ? b0 : (z == 1) ? b1 : b2;
    float* O          = (z == 0) ? O0 : (z == 1) ? O1 : O2;

    const int n0 = blockIdx.x * 128;
    const int m0 = blockIdx.y * 64;
    const int t = threadIdx.x;
    const int lane = t & 63;
    const int wave = t >> 6;
    const int l15 = lane & 15, l4 = lane >> 4;
    const int wm = (wave >> 1) * 32, wn = (wave & 1) * 64;

    __shared__ short As[64][72];
    __shared__ short Bs[128][72];

    f32x4 acc[2][4] = {};
    f32x4 areg[4], breg[8];

    #pragma unroll
    for (int i = 0; i < 4; ++i) {
        int lin = i * 256 + t;
        areg[i] = *(const f32x4*)(A + (size_t)(m0 + (lin >> 4)) * DM + (lin & 15) * 4);
    }
    #pragma unroll
    for (int i = 0; i < 8; ++i) {
        int lin = i * 256 + t;
        breg[i] = *(const f32x4*)(W + (size_t)(n0 + (lin >> 4)) * DM + (lin & 15) * 4);
    }

    for (int ks = 0; ks < DM / 64; ++ks) {
        #pragma unroll
        for (int i = 0; i < 4; ++i) {
            int lin = i * 256 + t;
            s16x4 a4;
            #pragma unroll
            for (int j = 0; j < 4; ++j) a4[j] = bfc(areg[i][j]);
            *(s16x4*)&As[lin >> 4][(lin & 15) * 4] = a4;
        }
        #pragma unroll
        for (int i = 0; i < 8; ++i) {
            int lin = i * 256 + t;
            s16x4 w4;
            #pragma unroll
            for (int j = 0; j < 4; ++j) w4[j] = bfc(breg[i][j]);
            *(s16x4*)&Bs[lin >> 4][(lin & 15) * 4] = w4;
        }
        __syncthreads();
        if (ks + 1 < DM / 64) {
            int k0 = (ks + 1) * 64;
            #pragma unroll
            for (int i = 0; i < 4; ++i) {
                int lin = i * 256 + t;
                areg[i] = *(const f32x4*)(A + (size_t)(m0 + (lin >> 4)) * DM + k0 + (lin & 15) * 4);
            }
            #pragma unroll
            for (int i = 0; i < 8; ++i) {
                int lin = i * 256 + t;
                breg[i] = *(const f32x4*)(W + (size_t)(n0 + (lin >> 4)) * DM + k0 + (lin & 15) * 4);
            }
        }
        #pragma unroll
        for (int kt = 0; kt < 2; ++kt) {
            s16x8 af[2], bfr[4];
            #pragma unroll
            for (int i = 0; i < 2; ++i)
                af[i]  = *(const s16x8*)&As[wm + i * 16 + l15][kt * 32 + l4 * 8];
            #pragma unroll
            for (int i = 0; i < 4; ++i)
                bfr[i] = *(const s16x8*)&Bs[wn + i * 16 + l15][kt * 32 + l4 * 8];
            #pragma unroll
            for (int mi = 0; mi < 2; ++mi)
                #pragma unroll
                for (int ni = 0; ni < 4; ++ni)
                    acc[mi][ni] = __builtin_amdgcn_mfma_f32_16x16x32_bf16(
                        af[mi], bfr[ni], acc[mi][ni], 0, 0, 0);
        }
        __syncthreads();
    }

    #pragma unroll
    for (int ni = 0; ni < 4; ++ni) {
        int col = n0 + wn + ni * 16 + l15;
        float bv = bias[col];
        #pragma unroll
        for (int mi = 0; mi < 2; ++mi) {
            int row = m0 + wm + mi * 16 + l4 * 4;
            #pragma unroll
            for (int r = 0; r < 4; ++r)
                O[(size_t)(row + r) * DM + col] = acc[mi][ni][r] + bv;
        }
    }
}

// ---------------- RMSNorm + RoPE; Q pre-scaled by 1/sqrt(128)*log2e -> bf16 ----------------
__global__ __launch_bounds__(256) void norm_rope(
    float* __restrict__ qf, float* __restrict__ kf, short* __restrict__ qbf,
    const float* __restrict__ gq, const float* __restrict__ gk,
    const float* __restrict__ freqs)
{
    const int buf = blockIdx.x >> 9;
    const int row = blockIdx.x & 511;
    const int t = threadIdx.x;
    float* src = buf ? kf : qf;
    const float* g = buf ? gk : gq;

    f32x2 v[6];
    float ss = 0.f;
    #pragma unroll
    for (int i = 0; i < 6; ++i) {
        int p = t + 256 * i;
        v[i] = *(const f32x2*)(src + (size_t)row * DM + 2 * p);
        ss += v[i][0] * v[i][0] + v[i][1] * v[i][1];
    }
    #pragma unroll
    for (int m = 1; m < 64; m <<= 1) ss += __shfl_xor(ss, m);
    __shared__ float red[4];
    if ((t & 63) == 0) red[t >> 6] = ss;
    __syncthreads();
    ss = red[0] + red[1] + red[2] + red[3];
    const float scale = rsqrtf(ss * (1.0f / DM) + 1e-6f);
    const float QS = 0.08838834764831845f * 1.4426950408889634f; // 1/sqrt(128)*log2e

    const int spos = row & 255;
    #pragma unroll
    for (int i = 0; i < 6; ++i) {
        int p = t + 256 * i;
        int d2 = p & 63;
        float fr = freqs[spos * 64 + d2];
        float snv, cs;
        __sincosf(fr, &snv, &cs);
        f32x2 gg = *(const f32x2*)(g + 2 * p);
        float re = v[i][0] * scale * gg[0];
        float im = v[i][1] * scale * gg[1];
        float re2 = re * cs - im * snv;
        float im2 = re * snv + im * cs;
        if (buf == 0) {
            re2 *= QS; im2 *= QS;
            unsigned pack = (unsigned)(unsigned short)bfc(re2)
                          | ((unsigned)(unsigned short)bfc(im2) << 16);
            *(unsigned*)(qbf + (size_t)row * DM + 2 * p) = pack;
        } else {
            f32x2 o; o[0] = re2; o[1] = im2;
            *(f32x2*)(src + (size_t)row * DM + 2 * p) = o;
        }
    }
}

// ---------------- Flash attention: swapped QK^T, in-reg P, dbuf LDS (1 barrier/tile),
// lazy cross-lane softmax (per-lane partials, reduce once at end) ----------------
// grid 432 (XCD-swizzled), 512 thr (8 waves), chunks of 15/14 key-tiles (64 keys each).
__global__ __launch_bounds__(512) void attn_fa(
    const short* __restrict__ qbf,
    const float* __restrict__ kf, const float* __restrict__ vf,
    const float* __restrict__ kcache, const float* __restrict__ vcache,
    float* __restrict__ partO, float* __restrict__ partM, float* __restrict__ partL)
{
    const int bid = blockIdx.x;               // 0..431
    const int linear = (bid & 7) * 54 + (bid >> 3);
    const int c  = linear / 48;
    const int bh = linear % 48;
    const int b = bh / NH, h = bh % NH;
    const int t = threadIdx.x, lane = t & 63, wave = t >> 6;
    const int l15 = lane & 15, l4 = lane >> 4;
    const int hoff = h * HD;

    __shared__ short KsA[2][64 * 128];   // [k][d] 256B rows, chunk-swizzled
    __shared__ short VtA[2][128 * 64];   // [d][k] 128B rows, chunk-swizzled

    // Q B-fragments
    s16x8 qb[2][4];
    #pragma unroll
    for (int nj = 0; nj < 2; ++nj) {
        int qrow = b * SN + wave * 32 + nj * 16 + l15;
        #pragma unroll
        for (int kt = 0; kt < 4; ++kt)
            qb[nj][kt] = *(const s16x8*)(qbf + (size_t)qrow * DM + hoff + kt * 32 + l4 * 8);
    }

    f32x4 acc[2][8] = {};
    float mrun[2] = {-INFINITY, -INFINITY};
    float lpart[2] = {0.f, 0.f};         // per-lane partial sums

    const int ts = (c < 6) ? c * 15 : 90 + (c - 6) * 14;   // first tile
    const int NT = (c < 6) ? 15 : 14;

    const float* kcB = kcache + (size_t)b * SCACHE * DM + hoff;
    const float* knB = kf     + (size_t)b * SN * DM + hoff;
    const float* vcB = vcache + (size_t)b * SCACHE * DM + hoff;
    const float* vnB = vf     + (size_t)b * SN * DM + hoff;

    auto kaddr = [&](int r, int col) -> const float* {
        return (r < SCACHE) ? (kcB + (size_t)r * DM + col)
                            : (knB + (size_t)(r - SCACHE) * DM + col);
    };
    auto vaddr = [&](int r, int col) -> const float* {
        return (r < SCACHE) ? (vcB + (size_t)r * DM + col)
                            : (vnB + (size_t)(r - SCACHE) * DM + col);
    };

    const int vrow = t & 63, vw = t >> 6;
    f32x4 kreg[4], vreg[4];

    // prologue: tile 0 loads
    {
        const int kr = ts * 64;
        #pragma unroll
        for (int i = 0; i < 4; ++i) {
            int lin = i * 512 + t;
            kreg[i] = *(const f32x4*)kaddr(kr + (lin >> 5), (lin & 31) * 4);
        }
        #pragma unroll
        for (int j = 0; j < 4; ++j)
            vreg[j] = *(const f32x4*)vaddr(kr + vrow, vw * 16 + j * 4);
    }

    const bool ghi = (l4 & 2) != 0;
    const bool gin = (l4 == 0) || (l4 == 3);

    for (int nt = 0; nt < NT; ++nt) {
        char* KsB = (char*)KsA[nt & 1];
        char* VtB = (char*)VtA[nt & 1];

        // ---- stage regs -> LDS buf[nt&1] (chunk-swizzled) ----
        #pragma unroll
        for (int i = 0; i < 4; ++i) {
            int lin = i * 512 + t;
            int row = lin >> 5, col4 = lin & 31;
            s16x4 k4;
            #pragma unroll
            for (int j = 0; j < 4; ++j) k4[j] = bfc(kreg[i][j]);
            *(s16x4*)(KsB + (row << 8) + ((((col4 >> 1) ^ row) & 15) << 4) + ((col4 & 1) << 3)) = k4;
        }
        #pragma unroll
        for (int j = 0; j < 4; ++j) {
            #pragma unroll
            for (int jj = 0; jj < 4; ++jj) {
                int d = vw * 16 + j * 4 + jj;
                *(short*)(VtB + (d << 7) + ((((vrow >> 3) ^ (d & 7))) << 4) + ((vrow & 7) << 1)) = bfc(vreg[j][jj]);
            }
        }
        __syncthreads();   // single barrier per tile (double-buffered)

        // ---- issue next-tile loads (fly across all compute) ----
        if (nt + 1 < NT) {
            const int kr1 = (ts + nt + 1) * 64;
            #pragma unroll
            for (int i = 0; i < 4; ++i) {
                int lin = i * 512 + t;
                kreg[i] = *(const f32x4*)kaddr(kr1 + (lin >> 5), (lin & 31) * 4);
            }
            #pragma unroll
            for (int j = 0; j < 4; ++j)
                vreg[j] = *(const f32x4*)vaddr(kr1 + vrow, vw * 16 + j * 4);
        }

        // ---- S^T = K * Q^T ----
        f32x4 st[4][2] = {};
        #pragma unroll
        for (int kt = 0; kt < 4; ++kt)
            #pragma unroll
            for (int mi = 0; mi < 4; ++mi) {
                int row = mi * 16 + l15;
                s16x8 kfr = *(const s16x8*)(KsB + (row << 8) + (((kt * 4 + l4) ^ l15) << 4));
                st[mi][0] = __builtin_amdgcn_mfma_f32_16x16x32_bf16(kfr, qb[0][kt], st[mi][0], 0, 0, 0);
                st[mi][1] = __builtin_amdgcn_mfma_f32_16x16x32_bf16(kfr, qb[1][kt], st[mi][1], 0, 0, 0);
            }

        // ---- online softmax, lazy cross-lane ----
        float lx0 = fmaxf(
            fmaxf(fmaxf(fmaxf(st[0][0][0], st[0][0][1]), fmaxf(st[0][0][2], st[0][0][3])),
                  fmaxf(fmaxf(st[1][0][0], st[1][0][1]), fmaxf(st[1][0][2], st[1][0][3]))),
            fmaxf(fmaxf(fmaxf(st[2][0][0], st[2][0][1]), fmaxf(st[2][0][2], st[2][0][3])),
                  fmaxf(fmaxf(st[3][0][0], st[3][0][1]), fmaxf(st[3][0][2], st[3][0][3]))));
        float lx1 = fmaxf(
            fmaxf(fmaxf(fmaxf(st[0][1][0], st[0][1][1]), fmaxf(st[0][1][2], st[0][1][3])),
                  fmaxf(fmaxf(st[1][1][0], st[1][1][1]), fmaxf(st[1][1][2], st[1][1][3]))),
            fmaxf(fmaxf(fmaxf(st[2][1][0], st[2][1][1]), fmaxf(st[2][1][2], st[2][1][3])),
                  fmaxf(fmaxf(st[3][1][0], st[3][1][1]), fmaxf(st[3][1][2], st[3][1][3]))));

        // defer-max: only when some lane's local max grows past mrun+8 do the full reduce
        if (!__all((lx0 <= mrun[0] + 8.0f) && (lx1 <= mrun[1] + 8.0f))) {
            float lm0 = fmaxf(lx0, __shfl_xor(lx0, 16)); lm0 = fmaxf(lm0, __shfl_xor(lm0, 32));
            float lm1 = fmaxf(lx1, __shfl_xor(lx1, 16)); lm1 = fmaxf(lm1, __shfl_xor(lm1, 32));
            float mn0 = fmaxf(mrun[0], lm0), mn1 = fmaxf(mrun[1], lm1);
            float c0 = exp2f(mrun[0] - mn0), c1 = exp2f(mrun[1] - mn1);
            mrun[0] = mn0; mrun[1] = mn1;
            lpart[0] *= c0; lpart[1] *= c1;
            #pragma unroll
            for (int df = 0; df < 8; ++df) { acc[0][df] *= c0; acc[1][df] *= c1; }
        }

        #pragma unroll
        for (int mi = 0; mi < 4; ++mi)
            #pragma unroll
            for (int r = 0; r < 4; ++r) {
                float p0 = exp2f(st[mi][0][r] - mrun[0]);
                float p1 = exp2f(st[mi][1][r] - mrun[1]);
                st[mi][0][r] = p0; st[mi][1][r] = p1;
                lpart[0] += p0; lpart[1] += p1;
            }

        // ---- pack P to bf16 pairs ----
        unsigned up[2][4][2];
        #pragma unroll
        for (int nj = 0; nj < 2; ++nj)
            #pragma unroll
            for (int mi = 0; mi < 4; ++mi)
                #pragma unroll
                for (int i = 0; i < 2; ++i)
                    up[nj][mi][i] = (unsigned)(unsigned short)bfc(st[mi][nj][2 * i])
                                  | ((unsigned)(unsigned short)bfc(st[mi][nj][2 * i + 1]) << 16);

        // ---- cross-group exchange -> PV B-frags ----
        s16x8 bp[2][2];
        #pragma unroll
        for (int nj = 0; nj < 2; ++nj)
            #pragma unroll
            for (int kt2 = 0; kt2 < 2; ++kt2) {
                unsigned own0 = ghi ? up[nj][kt2 * 2 + 1][0] : up[nj][kt2 * 2 + 0][0];
                unsigned own1 = ghi ? up[nj][kt2 * 2 + 1][1] : up[nj][kt2 * 2 + 0][1];
                unsigned alt0 = ghi ? up[nj][kt2 * 2 + 0][0] : up[nj][kt2 * 2 + 1][0];
                unsigned alt1 = ghi ? up[nj][kt2 * 2 + 0][1] : up[nj][kt2 * 2 + 1][1];
                unsigned o16_0 = __shfl_xor(own0, 16), o16_1 = __shfl_xor(own1, 16);
                unsigned o32_0 = __shfl_xor(alt0, 32), o32_1 = __shfl_xor(alt1, 32);
                unsigned o48_0 = __shfl_xor(alt0, 48), o48_1 = __shfl_xor(alt1, 48);
                u32x4 uu;
                uu[0] = gin ? (ghi ? o16_0 : own0) : (ghi ? o32_0 : o48_0);
                uu[1] = gin ? (ghi ? o16_1 : own1) : (ghi ? o32_1 : o48_1);
                uu[2] = gin ? (ghi ? own0 : o16_0) : (ghi ? o48_0 : o32_0);
                uu[3] = gin ? (ghi ? own1 : o16_1) : (ghi ? o48_1 : o32_1);
                bp[nj][kt2] = __builtin_bit_cast(s16x8, uu);
            }

        // ---- PV ----
        #pragma unroll
        for (int kt2 = 0; kt2 < 2; ++kt2)
            #pragma unroll
            for (int df = 0; df < 8; ++df) {
                int row = df * 16 + l15;
                s16x8 vfr = *(const s16x8*)(VtB + (row << 7) + (((kt2 * 4 + l4) ^ (row & 7)) << 4));
                acc[0][df] = __builtin_amdgcn_mfma_f32_16x16x32_bf16(vfr, bp[0][kt2], acc[0][df], 0, 0, 0);
                acc[1][df] = __builtin_amdgcn_mfma_f32_16x16x32_bf16(vfr, bp[1][kt2], acc[1][df], 0, 0, 0);
            }
    }

    // ---- final cross-lane sum of l (once) ----
    float l0 = lpart[0]; l0 += __shfl_xor(l0, 16); l0 += __shfl_xor(l0, 32);
    float l1 = lpart[1]; l1 += __shfl_xor(l1, 16); l1 += __shfl_xor(l1, 32);

    // ---- write partials ----
    #pragma unroll
    for (int nj = 0; nj < 2; ++nj) {
        size_t rowid = (size_t)bh * SN + wave * 32 + nj * 16 + l15;
        float* po = partO + (rowid * NCH + c) * HD + l4 * 4;
        #pragma unroll
        for (int df = 0; df < 8; ++df)
            *(f32x4*)(po + df * 16) = acc[nj][df];
        if (l4 == 0) {
            partM[rowid * NCH + c] = mrun[nj];
            partL[rowid * NCH + c] = (nj == 0) ? l0 : l1;
        }
    }
}

// ---------------- combine split-K partials ----------------
__global__ __launch_bounds__(128) void combine(
    const float* __restrict__ partO, const float* __restrict__ partM,
    const float* __restrict__ partL, float* __restrict__ attn)
{
    const int rowid = blockIdx.x;        // bh*256 + q
    const int bh = rowid >> 8, q = rowid & 255;
    const int b = bh / NH, h = bh % NH;
    const int d = threadIdx.x;

    float m[NCH];
    float M = -INFINITY;
    #pragma unroll
    for (int c = 0; c < NCH; ++c) { m[c] = partM[(size_t)rowid * NCH + c]; M = fmaxf(M, m[c]); }
    float L = 0.f, o = 0.f;
    #pragma unroll
    for (int c = 0; c < NCH; ++c) {
        float w = exp2f(m[c] - M);
        L += partL[(size_t)rowid * NCH + c] * w;
        o += partO[((size_t)rowid * NCH + c) * HD + d] * w;
    }
    attn[(size_t)(b * SN + q) * DM + h * HD + d] = o / L;
}

extern "C" void kernel_launch(void* const* d_in, const int* in_sizes, int n_in,
                              void* d_out, int out_size, void* d_ws, size_t ws_size,
                              hipStream_t stream) {
    const float* x      = (const float*)d_in[0];
    const float* freqs  = (const float*)d_in[1];
    const float* kcache = (const float*)d_in[2];
    const float* vcache = (const float*)d_in[3];
    const float* Wq = (const float*)d_in[4];
    const float* bq = (const float*)d_in[5];
    const float* Wk = (const float*)d_in[6];
    const float* bk = (const float*)d_in[7];
    const float* Wv = (const float*)d_in[8];
    const float* bv = (const float*)d_in[9];
    const float* Wo = (const float*)d_in[10];
    const float* bo = (const float*)d_in[11];
    const float* gq = (const float*)d_in[12];
    const float* gk = (const float*)d_in[13];
    float* out = (float*)d_out;

    auto al = [](size_t v) { return (v + 255) & ~(size_t)255; };
    const size_t SZ_QF  = (size_t)MR * DM * 4;
    const size_t SZ_QBF = (size_t)MR * DM * 2;
    const size_t SZ_PML = (size_t)48 * SN * NCH * 4;
    const size_t SZ_PO  = (size_t)48 * SN * NCH * HD * 4;

    char* ws = (char*)d_ws;
    float* qf   = (float*)ws; ws += al(SZ_QF);
    float* kfb  = (float*)ws; ws += al(SZ_QF);
    float* vfb  = (float*)ws; ws += al(SZ_QF);
    short* qbf  = (short*)ws; ws += al(SZ_QBF);
    float* pM   = (float*)ws; ws += al(SZ_PML);
    float* pL   = (float*)ws; ws += al(SZ_PML);
    float* attn = (float*)ws; ws += al(SZ_QF);
    float* pO   = (float*)ws; ws += al(SZ_PO);

    gemm_bias<<<dim3(24, 8, 3), 256, 0, stream>>>(x, Wq, Wk, Wv, bq, bk, bv, qf, kfb, vfb);
    norm_rope<<<dim3(1024), 256, 0, stream>>>(qf, kfb, qbf, gq, gk, freqs);
    attn_fa<<<dim3(432), 512, 0, stream>>>(qbf, kfb, vfb, kcache, vcache, pO, pM, pL);
    combine<<<dim3(12288), 128, 0, stream>>>(pO, pM, pL, attn);
    gemm_bias<<<dim3(24, 8, 1), 256, 0, stream>>>(attn, Wo, Wo, Wo, bo, bo, bo, out, out, out);
}